// Round 3
// baseline (3676.888 us; speedup 1.0000x reference)
//
#include <hip/hip_runtime.h>
#include <hip/hip_fp16.h>
#include <cmath>

#define LVL   16
#define TSIZE (1u << 19)
#define TMASK (TSIZE - 1u)
#define HID   32
#define PRIME1 2654435761u
#define PRIME2 805459861u
#define NGROUP 8

struct Scales { float s[LVL]; };

__device__ __forceinline__ float elu_f(float v) {
    return v > 0.0f ? v : expm1f(v);
}

// ---- per-level hash-grid encode: 8 gathers + trilinear ----
__device__ __forceinline__ float2 ld_entry(const float2* __restrict__ t, unsigned i) {
    return t[i];
}
__device__ __forceinline__ float2 ld_entry(const __half2* __restrict__ t, unsigned i) {
    return __half22float2(t[i]);
}

template <typename T2>
__device__ __forceinline__ float2 enc_level(float xn0, float xn1, float xn2, float s,
                                            const T2* __restrict__ tb)
{
    float px = xn0 * s, py = xn1 * s, pz = xn2 * s;
    float fx = floorf(px), fy = floorf(py), fz = floorf(pz);
    float wx = px - fx, wy = py - fy, wz = pz - fz;
    unsigned x0 = (unsigned)fx, y0 = (unsigned)fy, z0 = (unsigned)fz;

    unsigned hy0 = y0 * PRIME1, hy1 = hy0 + PRIME1;
    unsigned hz0 = z0 * PRIME2, hz1 = hz0 + PRIME2;
    unsigned b00 = hy0 ^ hz0, b10 = hy1 ^ hz0, b01 = hy0 ^ hz1, b11 = hy1 ^ hz1;

    float2 g000 = ld_entry(tb, ( x0       ^ b00) & TMASK);
    float2 g100 = ld_entry(tb, ((x0 + 1u) ^ b00) & TMASK);
    float2 g010 = ld_entry(tb, ( x0       ^ b10) & TMASK);
    float2 g110 = ld_entry(tb, ((x0 + 1u) ^ b10) & TMASK);
    float2 g001 = ld_entry(tb, ( x0       ^ b01) & TMASK);
    float2 g101 = ld_entry(tb, ((x0 + 1u) ^ b01) & TMASK);
    float2 g011 = ld_entry(tb, ( x0       ^ b11) & TMASK);
    float2 g111 = ld_entry(tb, ((x0 + 1u) ^ b11) & TMASK);

    float ux = 1.0f - wx, uy = 1.0f - wy, uz = 1.0f - wz;
    float c00 = uy*uz, c10 = wy*uz, c01 = uy*wz, c11 = wy*wz;

    float f0 = ux * (c00*g000.x + c10*g010.x + c01*g001.x + c11*g011.x)
             + wx * (c00*g100.x + c10*g110.x + c01*g101.x + c11*g111.x);
    float f1 = ux * (c00*g000.y + c10*g010.y + c01*g001.y + c11*g011.y)
             + wx * (c00*g100.y + c10*g110.y + c01*g101.y + c11*g111.y);
    return make_float2(f0, f1);
}

// ---- kernel 1: table fp32 -> fp16 ----
__global__ __launch_bounds__(256)
void convert_kernel(const float2* __restrict__ src, __half2* __restrict__ dst, int n_entries)
{
    int i = blockIdx.x * blockDim.x + threadIdx.x;
    int stride = gridDim.x * blockDim.x;
    for (; i < n_entries; i += stride) {
        float2 v = src[i];
        dst[i] = __floats2half2_rn(v.x, v.y);
    }
}

// ---- kernel 2: XCD-sharded hash encode. group g (= blockIdx%8, rides the
// round-robin block->XCD mapping) computes levels {g, g+8} for all points, so
// each XCD's 4MB L2 only ever sees ~4MB of fp16 table -> L2-resident gathers.
__global__ __launch_bounds__(256)
void hash_kernel(const float* __restrict__ x, const __half2* __restrict__ table,
                 float4* __restrict__ feats, int n, Scales sc)
{
    int g = blockIdx.x & (NGROUP - 1);
    int p = (blockIdx.x >> 3) * blockDim.x + threadIdx.x;
    if (p >= n) return;

    float xn0 = (x[3*p+0] + 1.0f) * 0.5f;
    float xn1 = (x[3*p+1] + 1.0f) * 0.5f;
    float xn2 = (x[3*p+2] + 1.0f) * 0.5f;

    int l0 = g, l1 = g + NGROUP;
    float2 fa = enc_level(xn0, xn1, xn2, sc.s[l0], table + (size_t)l0 * TSIZE);
    float2 fb = enc_level(xn0, xn1, xn2, sc.s[l1], table + (size_t)l1 * TSIZE);

    feats[(size_t)g * n + p] = make_float4(fa.x, fa.y, fb.x, fb.y);
}

// ---- kernel 3: MLP (fp32; weights wave-uniform) ----
__global__ __launch_bounds__(256)
void mlp_kernel(const float* __restrict__ x, const float4* __restrict__ feats,
                const float* __restrict__ W0, const float* __restrict__ b0,
                const float* __restrict__ W1, const float* __restrict__ b1,
                const float* __restrict__ Wout, const float* __restrict__ bout,
                float* __restrict__ out, int n)
{
    int p = blockIdx.x * blockDim.x + threadIdx.x;
    if (p >= n) return;

    float xn0 = (x[3*p+0] + 1.0f) * 0.5f;
    float xn1 = (x[3*p+1] + 1.0f) * 0.5f;
    float xn2 = (x[3*p+2] + 1.0f) * 0.5f;

    float acc[HID];
#pragma unroll
    for (int j = 0; j < HID; ++j)
        acc[j] = b0[j] + xn0 * W0[0*HID + j] + xn1 * W0[1*HID + j] + xn2 * W0[2*HID + j];

#pragma unroll
    for (int g = 0; g < NGROUP; ++g) {
        float4 f = feats[(size_t)g * n + p];
        // group g carries levels g (f.x,f.y) and g+8 (f.z,f.w);
        // feature (l,c) -> W0 row 3 + 2l + c
        const float* rA = W0 + (3 + 2*g) * HID;
        const float* rB = W0 + (4 + 2*g) * HID;
        const float* rC = W0 + (19 + 2*g) * HID;
        const float* rD = W0 + (20 + 2*g) * HID;
#pragma unroll
        for (int j = 0; j < HID; ++j)
            acc[j] += f.x * rA[j] + f.y * rB[j] + f.z * rC[j] + f.w * rD[j];
    }

    float h1v[HID];
#pragma unroll
    for (int j = 0; j < HID; ++j) h1v[j] = elu_f(acc[j]);

    float acc2[HID];
#pragma unroll
    for (int j = 0; j < HID; ++j) acc2[j] = b1[j];
#pragma unroll
    for (int k = 0; k < HID; ++k) {
        float hk = h1v[k];
        const float* w1r = W1 + k * HID;
#pragma unroll
        for (int j = 0; j < HID; ++j) acc2[j] += hk * w1r[j];
    }

    float o = bout[0];
#pragma unroll
    for (int k = 0; k < HID; ++k) o += elu_f(acc2[k]) * Wout[k];

    out[p] = o;
}

// ---- fallback: fully fused single kernel (templated on table dtype) ----
template <typename T2>
__global__ __launch_bounds__(256)
void fused_kernel(const float* __restrict__ x, const T2* __restrict__ table,
                  const float* __restrict__ W0, const float* __restrict__ b0,
                  const float* __restrict__ W1, const float* __restrict__ b1,
                  const float* __restrict__ Wout, const float* __restrict__ bout,
                  float* __restrict__ out, int n, Scales sc)
{
    int p = blockIdx.x * blockDim.x + threadIdx.x;
    if (p >= n) return;

    float xn0 = (x[3*p+0] + 1.0f) * 0.5f;
    float xn1 = (x[3*p+1] + 1.0f) * 0.5f;
    float xn2 = (x[3*p+2] + 1.0f) * 0.5f;

    float acc[HID];
#pragma unroll
    for (int j = 0; j < HID; ++j)
        acc[j] = b0[j] + xn0 * W0[0*HID + j] + xn1 * W0[1*HID + j] + xn2 * W0[2*HID + j];

#pragma unroll
    for (int l = 0; l < LVL; ++l) {
        float2 f = enc_level(xn0, xn1, xn2, sc.s[l], table + (size_t)l * TSIZE);
        const float* w0r0 = W0 + (3 + 2*l) * HID;
        const float* w0r1 = W0 + (4 + 2*l) * HID;
#pragma unroll
        for (int j = 0; j < HID; ++j)
            acc[j] += f.x * w0r0[j] + f.y * w0r1[j];
    }

    float h1v[HID];
#pragma unroll
    for (int j = 0; j < HID; ++j) h1v[j] = elu_f(acc[j]);

    float acc2[HID];
#pragma unroll
    for (int j = 0; j < HID; ++j) acc2[j] = b1[j];
#pragma unroll
    for (int k = 0; k < HID; ++k) {
        float hk = h1v[k];
        const float* w1r = W1 + k * HID;
#pragma unroll
        for (int j = 0; j < HID; ++j) acc2[j] += hk * w1r[j];
    }

    float o = bout[0];
#pragma unroll
    for (int k = 0; k < HID; ++k) o += elu_f(acc2[k]) * Wout[k];

    out[p] = o;
}

extern "C" void kernel_launch(void* const* d_in, const int* in_sizes, int n_in,
                              void* d_out, int out_size, void* d_ws, size_t ws_size,
                              hipStream_t stream)
{
    const float* x    = (const float*)d_in[0];
    const float* tb   = (const float*)d_in[1];
    const float* W0   = (const float*)d_in[2];
    const float* b0   = (const float*)d_in[3];
    const float* W1   = (const float*)d_in[4];
    const float* b1   = (const float*)d_in[5];
    const float* Wout = (const float*)d_in[6];
    const float* bo   = (const float*)d_in[7];
    float* out = (float*)d_out;

    int n = in_sizes[0] / 3;

    Scales sc;
    double B = exp(log(32.0) / 15.0);
    for (int l = 0; l < LVL; ++l)
        sc.s[l] = (float)(16.0 * pow(B, (double)l) - 1.0);

    const int n_entries = LVL * (int)TSIZE;              // 8.4M half2 entries
    const size_t table_bytes = (size_t)n_entries * 4;    // 33.5 MB
    const size_t feat_bytes  = (size_t)n * NGROUP * sizeof(float4); // 256 MB

    int block = 256;
    int pgrid = (n + block - 1) / block;

    if (ws_size >= table_bytes + feat_bytes) {
        __half2* htab = (__half2*)d_ws;
        float4* feats = (float4*)((char*)d_ws + table_bytes);
        convert_kernel<<<8192, block, 0, stream>>>((const float2*)tb, htab, n_entries);
        hash_kernel<<<pgrid * NGROUP, block, 0, stream>>>(x, htab, feats, n, sc);
        mlp_kernel<<<pgrid, block, 0, stream>>>(x, feats, W0, b0, W1, b1, Wout, bo, out, n);
    } else if (ws_size >= table_bytes) {
        __half2* htab = (__half2*)d_ws;
        convert_kernel<<<8192, block, 0, stream>>>((const float2*)tb, htab, n_entries);
        fused_kernel<__half2><<<pgrid, block, 0, stream>>>(x, htab, W0, b0, W1, b1, Wout, bo, out, n, sc);
    } else {
        fused_kernel<float2><<<pgrid, block, 0, stream>>>(x, (const float2*)tb, W0, b0, W1, b1, Wout, bo, out, n, sc);
    }
}

// Round 4
// 2745.617 us; speedup vs baseline: 1.3392x; 1.3392x over previous
//
#include <hip/hip_runtime.h>
#include <hip/hip_fp16.h>
#include <cmath>

#define LVL   16
#define TSIZE (1u << 19)
#define TMASK (TSIZE - 1u)
#define HID   32
#define PRIME1 2654435761u
#define PRIME2 805459861u
#define NGROUP 8

struct Scales { float s[LVL]; };

__device__ __forceinline__ float elu_f(float v) {
    return v > 0.0f ? v : expm1f(v);
}

__device__ __forceinline__ float2 enc_level_f32(float xn0, float xn1, float xn2, float s,
                                                const float2* __restrict__ tb)
{
    float px = xn0 * s, py = xn1 * s, pz = xn2 * s;
    float fx = floorf(px), fy = floorf(py), fz = floorf(pz);
    float wx = px - fx, wy = py - fy, wz = pz - fz;
    unsigned x0 = (unsigned)fx, y0 = (unsigned)fy, z0 = (unsigned)fz;

    unsigned hy0 = y0 * PRIME1, hy1 = hy0 + PRIME1;
    unsigned hz0 = z0 * PRIME2, hz1 = hz0 + PRIME2;
    unsigned b00 = hy0 ^ hz0, b10 = hy1 ^ hz0, b01 = hy0 ^ hz1, b11 = hy1 ^ hz1;

    float2 g000 = tb[( x0       ^ b00) & TMASK];
    float2 g100 = tb[((x0 + 1u) ^ b00) & TMASK];
    float2 g010 = tb[( x0       ^ b10) & TMASK];
    float2 g110 = tb[((x0 + 1u) ^ b10) & TMASK];
    float2 g001 = tb[( x0       ^ b01) & TMASK];
    float2 g101 = tb[((x0 + 1u) ^ b01) & TMASK];
    float2 g011 = tb[( x0       ^ b11) & TMASK];
    float2 g111 = tb[((x0 + 1u) ^ b11) & TMASK];

    float ux = 1.0f - wx, uy = 1.0f - wy, uz = 1.0f - wz;
    float c00 = uy*uz, c10 = wy*uz, c01 = uy*wz, c11 = wy*wz;

    float f0 = ux * (c00*g000.x + c10*g010.x + c01*g001.x + c11*g011.x)
             + wx * (c00*g100.x + c10*g110.x + c01*g101.x + c11*g111.x);
    float f1 = ux * (c00*g000.y + c10*g010.y + c01*g001.y + c11*g011.y)
             + wx * (c00*g100.y + c10*g110.y + c01*g101.y + c11*g111.y);
    return make_float2(f0, f1);
}

// ---- XCD-sharded hash encode, fp32 table (straight from d_in, no conversion).
// group g = blockIdx%8 rides the round-robin block->XCD mapping; it computes
// levels {g, g+8} for all points, so each XCD's 4MB L2 sees only ~4-8MB of
// table -> gathers become (mostly) L2-hits instead of L3-class latency.
__global__ __launch_bounds__(256)
void hash_kernel(const float* __restrict__ x, const float2* __restrict__ table,
                 ushort4* __restrict__ feats, int n, Scales sc)
{
    int g = blockIdx.x & (NGROUP - 1);
    int p = (blockIdx.x >> 3) * blockDim.x + threadIdx.x;
    if (p >= n) return;

    float xn0 = (x[3*p+0] + 1.0f) * 0.5f;
    float xn1 = (x[3*p+1] + 1.0f) * 0.5f;
    float xn2 = (x[3*p+2] + 1.0f) * 0.5f;

    int l0 = g, l1 = g + NGROUP;
    float2 fa = enc_level_f32(xn0, xn1, xn2, sc.s[l0], table + (size_t)l0 * TSIZE);
    float2 fb = enc_level_f32(xn0, xn1, xn2, sc.s[l1], table + (size_t)l1 * TSIZE);

    ushort4 pk;
    pk.x = __half_as_ushort(__float2half_rn(fa.x));
    pk.y = __half_as_ushort(__float2half_rn(fa.y));
    pk.z = __half_as_ushort(__float2half_rn(fb.x));
    pk.w = __half_as_ushort(__float2half_rn(fb.y));
    feats[(size_t)g * n + p] = pk;
}

// ---- MLP (fp32 math; weights wave-uniform; feats fp16 coalesced) ----
__global__ __launch_bounds__(256)
void mlp_kernel(const float* __restrict__ x, const ushort4* __restrict__ feats,
                const float* __restrict__ W0, const float* __restrict__ b0,
                const float* __restrict__ W1, const float* __restrict__ b1,
                const float* __restrict__ Wout, const float* __restrict__ bout,
                float* __restrict__ out, int n)
{
    int p = blockIdx.x * blockDim.x + threadIdx.x;
    if (p >= n) return;

    float xn0 = (x[3*p+0] + 1.0f) * 0.5f;
    float xn1 = (x[3*p+1] + 1.0f) * 0.5f;
    float xn2 = (x[3*p+2] + 1.0f) * 0.5f;

    float acc[HID];
#pragma unroll
    for (int j = 0; j < HID; ++j)
        acc[j] = b0[j] + xn0 * W0[0*HID + j] + xn1 * W0[1*HID + j] + xn2 * W0[2*HID + j];

#pragma unroll
    for (int g = 0; g < NGROUP; ++g) {
        ushort4 pk = feats[(size_t)g * n + p];
        float fA = __half2float(__ushort_as_half(pk.x));
        float fB = __half2float(__ushort_as_half(pk.y));
        float fC = __half2float(__ushort_as_half(pk.z));
        float fD = __half2float(__ushort_as_half(pk.w));
        const float* rA = W0 + (3 + 2*g) * HID;
        const float* rB = W0 + (4 + 2*g) * HID;
        const float* rC = W0 + (19 + 2*g) * HID;
        const float* rD = W0 + (20 + 2*g) * HID;
#pragma unroll
        for (int j = 0; j < HID; ++j)
            acc[j] += fA * rA[j] + fB * rB[j] + fC * rC[j] + fD * rD[j];
    }

    float h1v[HID];
#pragma unroll
    for (int j = 0; j < HID; ++j) h1v[j] = elu_f(acc[j]);

    float acc2[HID];
#pragma unroll
    for (int j = 0; j < HID; ++j) acc2[j] = b1[j];
#pragma unroll
    for (int k = 0; k < HID; ++k) {
        float hk = h1v[k];
        const float* w1r = W1 + k * HID;
#pragma unroll
        for (int j = 0; j < HID; ++j) acc2[j] += hk * w1r[j];
    }

    float o = bout[0];
#pragma unroll
    for (int k = 0; k < HID; ++k) o += elu_f(acc2[k]) * Wout[k];

    out[p] = o;
}

// ---- fallback: exact round-1 fused kernel (fp32, one thread/point) ----
__global__ __launch_bounds__(256)
void fused_fp32_kernel(const float* __restrict__ x, const float* __restrict__ table,
                       const float* __restrict__ W0, const float* __restrict__ b0,
                       const float* __restrict__ W1, const float* __restrict__ b1,
                       const float* __restrict__ Wout, const float* __restrict__ bout,
                       float* __restrict__ out, int n, Scales sc)
{
    int tid = blockIdx.x * blockDim.x + threadIdx.x;
    if (tid >= n) return;

    float xn0 = (x[3*tid+0] + 1.0f) * 0.5f;
    float xn1 = (x[3*tid+1] + 1.0f) * 0.5f;
    float xn2 = (x[3*tid+2] + 1.0f) * 0.5f;

    float acc[HID];
#pragma unroll
    for (int j = 0; j < HID; ++j)
        acc[j] = b0[j] + xn0 * W0[0*HID + j] + xn1 * W0[1*HID + j] + xn2 * W0[2*HID + j];

#pragma unroll
    for (int l = 0; l < LVL; ++l) {
        const float2* tb = (const float2*)table + (size_t)l * TSIZE;
        float2 f = enc_level_f32(xn0, xn1, xn2, sc.s[l], tb);
        const float* w0r0 = W0 + (3 + 2*l) * HID;
        const float* w0r1 = W0 + (4 + 2*l) * HID;
#pragma unroll
        for (int j = 0; j < HID; ++j)
            acc[j] += f.x * w0r0[j] + f.y * w0r1[j];
    }

    float h1v[HID];
#pragma unroll
    for (int j = 0; j < HID; ++j) h1v[j] = elu_f(acc[j]);

    float acc2[HID];
#pragma unroll
    for (int j = 0; j < HID; ++j) acc2[j] = b1[j];
#pragma unroll
    for (int k = 0; k < HID; ++k) {
        float hk = h1v[k];
        const float* w1r = W1 + k * HID;
#pragma unroll
        for (int j = 0; j < HID; ++j) acc2[j] += hk * w1r[j];
    }

    float o = bout[0];
#pragma unroll
    for (int k = 0; k < HID; ++k) o += elu_f(acc2[k]) * Wout[k];

    out[tid] = o;
}

extern "C" void kernel_launch(void* const* d_in, const int* in_sizes, int n_in,
                              void* d_out, int out_size, void* d_ws, size_t ws_size,
                              hipStream_t stream)
{
    const float* x    = (const float*)d_in[0];
    const float* tb   = (const float*)d_in[1];
    const float* W0   = (const float*)d_in[2];
    const float* b0   = (const float*)d_in[3];
    const float* W1   = (const float*)d_in[4];
    const float* b1   = (const float*)d_in[5];
    const float* Wout = (const float*)d_in[6];
    const float* bo   = (const float*)d_in[7];
    float* out = (float*)d_out;

    int n = in_sizes[0] / 3;

    Scales sc;
    double B = exp(log(32.0) / 15.0);
    for (int l = 0; l < LVL; ++l)
        sc.s[l] = (float)(16.0 * pow(B, (double)l) - 1.0);

    const size_t feat_bytes = (size_t)n * NGROUP * sizeof(ushort4); // 128 MB @ n=2M
    int block = 256;
    int pgrid = (n + block - 1) / block;

    if (ws_size >= feat_bytes) {
        ushort4* feats = (ushort4*)d_ws;
        hash_kernel<<<pgrid * NGROUP, block, 0, stream>>>(x, (const float2*)tb, feats, n, sc);
        mlp_kernel<<<pgrid, block, 0, stream>>>(x, feats, W0, b0, W1, b1, Wout, bo, out, n);
    } else {
        fused_fp32_kernel<<<pgrid, block, 0, stream>>>(x, tb, W0, b0, W1, b1, Wout, bo, out, n, sc);
    }
}